// Round 13
// baseline (48136.972 us; speedup 1.0000x reference)
//
#include <hip/hip_runtime.h>
#include <math.h>

#define NBLK 128
#define NTHR 512
#define NPOS 3168     // 99 steps * 32 batch
#define NSTAGES 3177  // last proj-phase2 at s = 3167 + 9
#define HIDN 512
#define TT 2048
#define LL 100

__device__ __forceinline__ float aload(const float* p) {
  return __hip_atomic_load((float*)p, __ATOMIC_RELAXED, __HIP_MEMORY_SCOPE_AGENT);
}
__device__ __forceinline__ void astore(float* p, float v) {
  __hip_atomic_store(p, v, __ATOMIC_RELAXED, __HIP_MEMORY_SCOPE_AGENT);
}
__device__ __forceinline__ int aload_i(const int* p) {
  return __hip_atomic_load((int*)p, __ATOMIC_RELAXED, __HIP_MEMORY_SCOPE_AGENT);
}
__device__ __forceinline__ void astore_i(int* p, int v) {
  __hip_atomic_store(p, v, __ATOMIC_RELAXED, __HIP_MEMORY_SCOPE_AGENT);
}
__device__ __forceinline__ float wsum(float v) {
#pragma unroll
  for (int o = 32; o; o >>= 1) v += __shfl_xor(v, o);
  return v;
}
__device__ __forceinline__ float wmax(float v) {
#pragma unroll
  for (int o = 32; o; o >>= 1) v = fmaxf(v, __shfl_xor(v, o));
  return v;
}
__device__ __forceinline__ float sigm(float x) { return 1.f / (1.f + expf(-x)); }

extern "C" __global__ void speller_init(float* ws) {
  const int i = blockIdx.x * blockDim.x + threadIdx.x;
  if (i < 5120) ws[i] = 0.f;  // arrive flags (2048 ints) + h double buffers (3072 floats)
}

// r9 structure (ONE grid serialization point per stage — r12 lesson: a second
// flag family doubles barrier latency on the critical path) + stage-top
// register hoists (all prior-stage data is ready at stage top under the
// single end-of-stage barrier) + cross-barrier prefetch of CONSTANT ctx_t
// rows (issued after flag post, in flight during the poll spin).
extern "C" __global__ __launch_bounds__(NTHR, 2)
void speller_main(const float* __restrict__ ctx_t, const int* __restrict__ gt,
                  const float* __restrict__ emb, const float* __restrict__ w_out,
                  const float* __restrict__ b_out,
                  const float* __restrict__ wi0, const float* __restrict__ wh0,
                  const float* __restrict__ bi0, const float* __restrict__ bh0,
                  const float* __restrict__ wi1, const float* __restrict__ wh1,
                  const float* __restrict__ bi1, const float* __restrict__ bh1,
                  const float* __restrict__ wi2, const float* __restrict__ wh2,
                  const float* __restrict__ bi2, const float* __restrict__ bh2,
                  float* __restrict__ out, float* __restrict__ ws)
{
  const int bid = blockIdx.x, tid = threadIdx.x;
  const int lane = tid & 63, wv = tid >> 6;
  const int ub = bid * 4;  // this block's 4 hidden units (per layer)

  // ---------------- workspace layout (201,856 floats = 807.4 KB) ----------------
  int*   arrive   = (int*)ws;               // [128][16] one cacheline per block
  float* h_buf    = ws + 2048;              // [2][3][512]
  float* rnn_ring = ws + 5120;              // [8][512]
  float* ctx_ring = ws + 9216;              // [64][512]
  float* e_ring   = ws + 41984;             // [4][2048]
  float* w_ring   = ws + 50176;             // [2][2048]
  float* P_ring   = ws + 54272;             // [2][128][512]
  float* Q_ring   = ws + 185344;            // [2][16][512]
  float* z_ring   = ws + 201728;            // [2][64]

  __shared__ float sro[HIDN];   // rnn_out for attention energies
  __shared__ float swex[16];    // this block's 16 attention weights
  __shared__ float gates[48];   // l*16 + g*4 + q
  __shared__ float csto[12];    // cell state, 4 units x 3 layers

  if (tid < 12) csto[tid] = 0.f;

  // ---------------- weight preload (r9-identical mapping) ----------------
  const int lyr = wv >> 1;  // 0..2 for wv 0..5
  float wreg[8][17];
  float bsum[8];
  if (wv < 6) {
    if (lyr == 0) {
#pragma unroll
      for (int r = 0; r < 8; ++r) {
        const int R = (wv * 2 + (r >> 2)) * 512 + ub + (r & 3);
#pragma unroll
        for (int k = 0; k < 9; ++k) wreg[r][k] = wi0[(size_t)R * 576 + k * 64 + lane];
#pragma unroll
        for (int k = 0; k < 8; ++k) wreg[r][9 + k] = wh0[(size_t)R * 512 + k * 64 + lane];
        bsum[r] = bi0[R] + bh0[R];
      }
    } else {
      const float* wiL = (lyr == 1) ? wi1 : wi2;
      const float* whL = (lyr == 1) ? wh1 : wh2;
      const float* biL = (lyr == 1) ? bi1 : bi2;
      const float* bhL = (lyr == 1) ? bh1 : bh2;
#pragma unroll
      for (int r = 0; r < 8; ++r) {
        const int R = ((wv & 1) * 2 + (r >> 2)) * 512 + ub + (r & 3);
#pragma unroll
        for (int k = 0; k < 8; ++k) wreg[r][k] = wiL[(size_t)R * 512 + k * 64 + lane];
#pragma unroll
        for (int k = 0; k < 8; ++k) wreg[r][8 + k] = whL[(size_t)R * 512 + k * 64 + lane];
        bsum[r] = biL[R] + bhL[R];
      }
    }
  }
  // projection weights: wave 6 of blocks 0..63 holds w_out row `bid`
  float wp[16];
  float bz = 0.f;
  if (bid < 64 && wv == 6) {
#pragma unroll
    for (int k = 0; k < 16; ++k) wp[k] = w_out[(size_t)bid * 1024 + k * 64 + lane];
    bz = b_out[bid];
  }

  // cross-barrier ctx_t prefetch registers (constant data; loop-carried)
  float ca0[8], ca1[8], cc[16];

  for (int s = 0; s < NSTAGES; ++s) {
    const float* hb = h_buf + (s & 1) * 1536;
    const int p1 = s - 3, p2 = s - 4, p3 = s - 5, p4 = s - 6,
              p5 = s - 7, p6 = s - 8, p7 = s - 9;

    // ======== stage top: all prior-stage data is barrier-ordered and ready ========
    // LDS staging
    if (p1 >= 0 && p1 < NPOS) sro[tid] = aload(rnn_ring + (p1 & 7) * 512 + tid);
    if (p3 >= 0 && p3 < NPOS && tid < 16)
      swex[tid] = aload(w_ring + (p3 & 1) * 2048 + bid * 16 + tid);

    // hoisted register gathers (block/wave-specialized)
    float pp[8];
    if (bid >= 64 && bid < 80 && p4 >= 0 && p4 < NPOS) {
      const float* Pb = P_ring + (p4 & 1) * (128 * 512) + ((bid - 64) * 8) * 512;
#pragma unroll
      for (int k = 0; k < 8; ++k) pp[k] = aload(Pb + k * 512 + tid);
    }
    float qq[16];
    if (bid == 80 && p5 >= 0 && p5 < NPOS) {
      const float* Qb = Q_ring + (p5 & 1) * 8192;
#pragma unroll
      for (int k = 0; k < 16; ++k) qq[k] = aload(Qb + k * 512 + tid);
    }
    float ee[32];
    if (bid == 81 && wv == 7 && p2 >= 0 && p2 < NPOS) {
      const float* eb = e_ring + (p2 & 3) * 2048;
#pragma unroll
      for (int k = 0; k < 32; ++k) ee[k] = aload(eb + k * 64 + lane);
    }
    float r6[8], c6[8];
    if (bid < 64 && wv == 6 && p6 >= 0 && p6 < NPOS) {
      const float* rr6 = rnn_ring + (p6 & 7) * 512;
      const float* cr6 = ctx_ring + (p6 & 63) * 512;
#pragma unroll
      for (int k = 0; k < 8; ++k) {
        r6[k] = aload(rr6 + k * 64 + lane);
        c6[k] = aload(cr6 + k * 64 + lane);
      }
    }
    float zz = 0.f;
    if (bid == 82 && wv == 7 && p7 >= 0 && p7 < NPOS)
      zz = aload(z_ring + (p7 & 1) * 64 + lane);

    // ---- LSTM gather + register dot products (waves 0..5) ----
    if (wv < 6) {
      const int pL = s - lyr;
      if (pL >= 0 && pL < NPOS) {
        if (lyr == 0) {
          float x[17];
          const int b0 = s & 31, t0 = s >> 5;
          const int g0 = gt[b0 * LL + t0];
          if (t0 == 0) {
            x[0] = (lane == g0) ? 1.f : 0.f;
            const float* cb = ctx_t + (size_t)b0 * TT * HIDN;
#pragma unroll
            for (int k = 0; k < 8; ++k) x[1 + k] = cb[k * 64 + lane];
          } else {
            x[0] = emb[g0 * 64 + lane];
            const float* cr = ctx_ring + ((s - 32) & 63) * 512;
#pragma unroll
            for (int k = 0; k < 8; ++k) x[1 + k] = aload(cr + k * 64 + lane);
          }
#pragma unroll
          for (int k = 0; k < 8; ++k) x[9 + k] = aload(hb + k * 64 + lane);
#pragma unroll
          for (int r = 0; r < 8; ++r) {
            float a = 0.f;
#pragma unroll
            for (int k = 0; k < 17; ++k) a += wreg[r][k] * x[k];
            a = wsum(a) + bsum[r];
            if (lane == 0) gates[(wv * 2 + (r >> 2)) * 4 + (r & 3)] = a;
          }
        } else {
          const int base = (lyr - 1) * 512;  // input = h_{lyr-1}, recur = h_{lyr}
          float xx[16];
#pragma unroll
          for (int k = 0; k < 8; ++k) xx[k]     = aload(hb + base + k * 64 + lane);
#pragma unroll
          for (int k = 0; k < 8; ++k) xx[8 + k] = aload(hb + base + 512 + k * 64 + lane);
#pragma unroll
          for (int r = 0; r < 8; ++r) {
            float a = 0.f;
#pragma unroll
            for (int k = 0; k < 16; ++k) a += wreg[r][k] * xx[k];
            a = wsum(a) + bsum[r];
            if (lane == 0) gates[lyr * 16 + ((wv & 1) * 2 + (r >> 2)) * 4 + (r & 3)] = a;
          }
        }
      }
    }
    __syncthreads();  // gates, sro, swex visible block-wide

    // ---- cell update (4 units x 3 layers) ----
    if (tid < 12) {
      const int l = tid >> 2, q = tid & 3;
      const int pl = s - l;
      if (pl >= 0 && pl < NPOS) {
        const float gi = gates[l * 16 + q];
        const float gf = gates[l * 16 + 4 + q];
        const float gg = gates[l * 16 + 8 + q];
        const float go = gates[l * 16 + 12 + q];
        const float cn = sigm(gf) * csto[tid] + sigm(gi) * tanhf(gg);
        const float hn = sigm(go) * tanhf(cn);
        csto[tid] = cn;
        const int u = ub + q;
        astore(h_buf + ((s + 1) & 1) * 1536 + l * 512 + u, hn);
        if (l == 2) astore(rnn_ring + (pl & 7) * 512 + u, hn);
      }
    }

    // ---- attn A: energies from prefetched ctx_t rows (2 per wave) ----
    if (p1 >= 0 && p1 < NPOS) {
      float a0 = 0.f, a1 = 0.f;
#pragma unroll
      for (int k = 0; k < 8; ++k) {
        a0 += ca0[k] * sro[k * 64 + lane];
        a1 += ca1[k] * sro[k * 64 + lane];
      }
      a0 = wsum(a0);
      a1 = wsum(a1);
      if (lane == 0) {
        float* eb = e_ring + (p1 & 3) * 2048 + bid * 16 + wv * 2;
        astore(eb, a0);
        astore(eb + 1, a1);
      }
    }

    // ---- attn C: pure compute (cc prefetched across barrier) ----
    if (p3 >= 0 && p3 < NPOS) {
      float a = 0.f;
#pragma unroll
      for (int j = 0; j < 16; ++j) a += swex[j] * cc[j];
      astore(P_ring + (p3 & 1) * (128 * 512) + bid * 512 + tid, a);
    }

    // ---- attn D1: 128 -> 16 combine (blocks 64..79, pp hoisted) ----
    if (bid >= 64 && bid < 80 && p4 >= 0 && p4 < NPOS) {
      float q0 = 0.f;
#pragma unroll
      for (int k = 0; k < 8; ++k) q0 += pp[k];
      astore(Q_ring + (p4 & 1) * 8192 + (bid - 64) * 512 + tid, q0);
    }

    // ---- attn D2: 16 -> 1 combine (block 80, qq hoisted) ----
    if (bid == 80 && p5 >= 0 && p5 < NPOS) {
      float c0 = 0.f;
#pragma unroll
      for (int k = 0; k < 16; ++k) c0 += qq[k];
      astore(ctx_ring + (p5 & 63) * 512 + tid, c0);
    }

    // ---- attn B: global softmax (block 81, wave 7, ee hoisted) ----
    if (bid == 81 && wv == 7 && p2 >= 0 && p2 < NPOS) {
      float m = ee[0];
#pragma unroll
      for (int k = 1; k < 32; ++k) m = fmaxf(m, ee[k]);
      m = wmax(m);
      float ssum = 0.f;
#pragma unroll
      for (int k = 0; k < 32; ++k) { ee[k] = expf(ee[k] - m); ssum += ee[k]; }
      ssum = wsum(ssum);
      const float inv = 1.f / ssum;
      float* wb = w_ring + (p2 & 1) * 2048;
#pragma unroll
      for (int k = 0; k < 32; ++k) astore(wb + k * 64 + lane, ee[k] * inv);
    }

    // ---- proj1: pure compute (r6/c6 hoisted; wave 6 of blocks 0..63) ----
    if (bid < 64 && wv == 6 && p6 >= 0 && p6 < NPOS) {
      float a = 0.f;
#pragma unroll
      for (int k = 0; k < 8; ++k) a += wp[k] * r6[k] + wp[8 + k] * c6[k];
      a = wsum(a);
      if (lane == 0) astore(z_ring + (p6 & 1) * 64 + bid, a + bz);
    }

    // ---- proj2: log_softmax + output write (block 82, wave 7, zz hoisted) ----
    if (bid == 82 && wv == 7 && p7 >= 0 && p7 < NPOS) {
      const float M = wmax(zz);
      const float ls = M + logf(wsum(expf(zz - M)));
      out[((size_t)(p7 & 31) * 99 + (p7 >> 5)) * 64 + lane] = zz - ls;
    }

    // ======== single grid barrier (r9-proven) ========
    asm volatile("s_waitcnt vmcnt(0)" ::: "memory");
    __syncthreads();
    if (tid == 0) astore_i(arrive + bid * 16, s + 1);

    // ---- cross-barrier prefetch of CONSTANT ctx_t for stage s+1 ----
    // Issued after the drain+flag so the loads fly during the poll spin.
    {
      const int p1n = s - 2;  // (s+1)-3
      if (p1n >= 0 && p1n < NPOS) {
        const float* c0p = ctx_t + ((size_t)(p1n & 31) * TT + bid * 16 + wv * 2) * HIDN;
#pragma unroll
        for (int k = 0; k < 8; ++k) {
          ca0[k] = c0p[k * 64 + lane];
          ca1[k] = c0p[HIDN + k * 64 + lane];
        }
      }
      const int p3n = s - 4;  // (s+1)-5
      if (p3n >= 0 && p3n < NPOS) {
        const float* cb3 = ctx_t + ((size_t)(p3n & 31) * TT + bid * 16) * HIDN;
#pragma unroll
        for (int j = 0; j < 16; ++j) cc[j] = cb3[j * HIDN + tid];
      }
    }

    // ---- poll (relaxed; r9-proven) ----
    if (tid < NBLK)
      while (aload_i(arrive + tid * 16) < s + 1) __builtin_amdgcn_s_sleep(1);
    asm volatile("" ::: "memory");
    __syncthreads();
  }
}

extern "C" void kernel_launch(void* const* d_in, const int* in_sizes, int n_in,
                              void* d_out, int out_size, void* d_ws, size_t ws_size,
                              hipStream_t stream) {
  (void)in_sizes; (void)n_in; (void)out_size; (void)ws_size;
  const float* ctx_t = (const float*)d_in[0];
  const int*   gt    = (const int*)d_in[1];
  const float* emb   = (const float*)d_in[3];
  const float* w_out = (const float*)d_in[4];
  const float* b_out = (const float*)d_in[5];
  const float* wi0 = (const float*)d_in[6];
  const float* wh0 = (const float*)d_in[7];
  const float* bi0 = (const float*)d_in[8];
  const float* bh0 = (const float*)d_in[9];
  const float* wi1 = (const float*)d_in[10];
  const float* wh1 = (const float*)d_in[11];
  const float* bi1 = (const float*)d_in[12];
  const float* bh1 = (const float*)d_in[13];
  const float* wi2 = (const float*)d_in[14];
  const float* wh2 = (const float*)d_in[15];
  const float* bi2 = (const float*)d_in[16];
  const float* bh2 = (const float*)d_in[17];
  float* out = (float*)d_out;
  float* ws  = (float*)d_ws;

  hipLaunchKernelGGL(speller_init, dim3(20), dim3(256), 0, stream, ws);

  hipLaunchKernelGGL(speller_main, dim3(NBLK), dim3(NTHR), 0, stream,
                     ctx_t, gt, emb, w_out, b_out,
                     wi0, wh0, bi0, bh0,
                     wi1, wh1, bi1, bh1,
                     wi2, wh2, bi2, bh2,
                     out, ws);
}

// Round 14
// 43384.235 us; speedup vs baseline: 1.1095x; 1.1095x over previous
//
#include <hip/hip_runtime.h>
#include <math.h>

#define NBLK 128
#define NTHR 512
#define NPOS 3168     // 99 steps * 32 batch
#define NSTAGES 3177  // last proj-phase2 at s = 3167 + 9
#define HIDN 512
#define TT 2048
#define LL 100

__device__ __forceinline__ float aload(const float* p) {
  return __hip_atomic_load((float*)p, __ATOMIC_RELAXED, __HIP_MEMORY_SCOPE_AGENT);
}
__device__ __forceinline__ void astore(float* p, float v) {
  __hip_atomic_store(p, v, __ATOMIC_RELAXED, __HIP_MEMORY_SCOPE_AGENT);
}
__device__ __forceinline__ int aload_i(const int* p) {
  return __hip_atomic_load((int*)p, __ATOMIC_RELAXED, __HIP_MEMORY_SCOPE_AGENT);
}
__device__ __forceinline__ void astore_i(int* p, int v) {
  __hip_atomic_store(p, v, __ATOMIC_RELAXED, __HIP_MEMORY_SCOPE_AGENT);
}
__device__ __forceinline__ float wsum(float v) {
#pragma unroll
  for (int o = 32; o; o >>= 1) v += __shfl_xor(v, o);
  return v;
}
__device__ __forceinline__ float wmax(float v) {
#pragma unroll
  for (int o = 32; o; o >>= 1) v = fmaxf(v, __shfl_xor(v, o));
  return v;
}
__device__ __forceinline__ float sigm(float x) { return 1.f / (1.f + expf(-x)); }

extern "C" __global__ void speller_init(float* ws) {
  const int i = blockIdx.x * blockDim.x + threadIdx.x;
  if (i < 5120) ws[i] = 0.f;  // padded arrive flags (2048 ints) + h double buffers (3072 floats)
}

// r9 skeleton (single end-of-stage barrier, relaxed flags — proven 24.7 ms).
// Delta vs r9: attnA (ca0/ca1) and attnC (cc) global loads hoisted to stage
// top WITHIN the stage (short live range, dead before the barrier). r13
// lesson: loop-carried prefetch regs spill to scratch (+2.9 GB FETCH); the
// unified VGPR+AGPR budget at (512,2) leaves only ~50 floats of headroom
// above wreg[136], so only these two every-block hoists are taken.
extern "C" __global__ __launch_bounds__(NTHR, 2)
void speller_main(const float* __restrict__ ctx_t, const int* __restrict__ gt,
                  const float* __restrict__ emb, const float* __restrict__ w_out,
                  const float* __restrict__ b_out,
                  const float* __restrict__ wi0, const float* __restrict__ wh0,
                  const float* __restrict__ bi0, const float* __restrict__ bh0,
                  const float* __restrict__ wi1, const float* __restrict__ wh1,
                  const float* __restrict__ bi1, const float* __restrict__ bh1,
                  const float* __restrict__ wi2, const float* __restrict__ wh2,
                  const float* __restrict__ bi2, const float* __restrict__ bh2,
                  float* __restrict__ out, float* __restrict__ ws)
{
  const int bid = blockIdx.x, tid = threadIdx.x;
  const int lane = tid & 63, wv = tid >> 6;
  const int ub = bid * 4;  // this block's 4 hidden units (per layer)

  // ---------------- workspace layout (197,760 floats = 791 KB) ----------------
  int*   arrive   = (int*)ws;               // [128][16] one cacheline per block
  float* h_buf    = ws + 2048;              // [2][3][512]
  float* rnn_ring = ws + 5120;              // [8][512]
  float* ctx_ring = ws + 9216;              // [64][512]
  float* e_ring   = ws + 41984;             // [2][2048]
  float* w_ring   = ws + 46080;             // [2][2048]
  float* P_ring   = ws + 50176;             // [2][128][512]
  float* Q_ring   = ws + 181248;            // [2][16][512]
  float* z_ring   = ws + 197632;            // [2][64]

  __shared__ float sro[HIDN];   // rnn_out for attention energies
  __shared__ float swex[16];    // this block's 16 attention weights (phase C)
  __shared__ float gates[48];   // l*16 + g*4 + q
  __shared__ float csto[12];    // cell state, 4 units x 3 layers

  if (tid < 12) csto[tid] = 0.f;

  // ---------------- weight preload (r9-identical mapping) ----------------
  const int lyr = wv >> 1;  // 0..2 for wv 0..5
  float wreg[8][17];
  float bsum[8];
  if (wv < 6) {
    if (lyr == 0) {
#pragma unroll
      for (int r = 0; r < 8; ++r) {
        const int R = (wv * 2 + (r >> 2)) * 512 + ub + (r & 3);
#pragma unroll
        for (int k = 0; k < 9; ++k) wreg[r][k] = wi0[(size_t)R * 576 + k * 64 + lane];
#pragma unroll
        for (int k = 0; k < 8; ++k) wreg[r][9 + k] = wh0[(size_t)R * 512 + k * 64 + lane];
        bsum[r] = bi0[R] + bh0[R];
      }
    } else {
      const float* wiL = (lyr == 1) ? wi1 : wi2;
      const float* whL = (lyr == 1) ? wh1 : wh2;
      const float* biL = (lyr == 1) ? bi1 : bi2;
      const float* bhL = (lyr == 1) ? bh1 : bh2;
#pragma unroll
      for (int r = 0; r < 8; ++r) {
        const int R = ((wv & 1) * 2 + (r >> 2)) * 512 + ub + (r & 3);
#pragma unroll
        for (int k = 0; k < 8; ++k) wreg[r][k] = wiL[(size_t)R * 512 + k * 64 + lane];
#pragma unroll
        for (int k = 0; k < 8; ++k) wreg[r][8 + k] = whL[(size_t)R * 512 + k * 64 + lane];
        bsum[r] = biL[R] + bhL[R];
      }
    }
  }
  // projection weights: wave 6 of blocks 0..63 holds w_out row `bid`
  float wp[16];
  float bz = 0.f;
  if (bid < 64 && wv == 6) {
#pragma unroll
    for (int k = 0; k < 16; ++k) wp[k] = w_out[(size_t)bid * 1024 + k * 64 + lane];
    bz = b_out[bid];
  }

  for (int s = 0; s < NSTAGES; ++s) {
    const float* hb = h_buf + (s & 1) * 1536;
    const int p1 = s - 3, p2 = s - 4, p3 = s - 5, p4 = s - 6,
              p5 = s - 7, p6 = s - 8, p7 = s - 9;

    // ---- stage-top staging: LDS + within-stage register hoists ----
    if (p1 >= 0 && p1 < NPOS) sro[tid] = aload(rnn_ring + (p1 & 7) * 512 + tid);
    if (p3 >= 0 && p3 < NPOS && tid < 16)
      swex[tid] = aload(w_ring + (p3 & 1) * 2048 + bid * 16 + tid);

    // attnA rows (constant ctx_t): issue now, consume after sync#1
    float ca0[8], ca1[8];
    if (p1 >= 0 && p1 < NPOS) {
      const float* c0 = ctx_t + ((size_t)(p1 & 31) * TT + bid * 16 + wv * 2) * HIDN;
#pragma unroll
      for (int k = 0; k < 8; ++k) {
        ca0[k] = c0[k * 64 + lane];
        ca1[k] = c0[HIDN + k * 64 + lane];
      }
    }
    // attnC column (constant ctx_t): issue now, consume after sync#1
    float cc[16];
    if (p3 >= 0 && p3 < NPOS) {
      const float* cb3 = ctx_t + ((size_t)(p3 & 31) * TT + bid * 16) * HIDN;
#pragma unroll
      for (int j = 0; j < 16; ++j) cc[j] = cb3[j * HIDN + tid];
    }

    // ---- LSTM gather + register dot products (waves 0..5) ----
    if (wv < 6) {
      const int pL = s - lyr;
      if (pL >= 0 && pL < NPOS) {
        if (lyr == 0) {
          float x[17];
          const int b0 = s & 31, t0 = s >> 5;
          const int g0 = gt[b0 * LL + t0];
          if (t0 == 0) {
            x[0] = (lane == g0) ? 1.f : 0.f;
            const float* cb = ctx_t + (size_t)b0 * TT * HIDN;
#pragma unroll
            for (int k = 0; k < 8; ++k) x[1 + k] = cb[k * 64 + lane];
          } else {
            x[0] = emb[g0 * 64 + lane];
            const float* cr = ctx_ring + ((s - 32) & 63) * 512;
#pragma unroll
            for (int k = 0; k < 8; ++k) x[1 + k] = aload(cr + k * 64 + lane);
          }
#pragma unroll
          for (int k = 0; k < 8; ++k) x[9 + k] = aload(hb + k * 64 + lane);
#pragma unroll
          for (int r = 0; r < 8; ++r) {
            float a = 0.f;
#pragma unroll
            for (int k = 0; k < 17; ++k) a += wreg[r][k] * x[k];
            a = wsum(a) + bsum[r];
            if (lane == 0) gates[(wv * 2 + (r >> 2)) * 4 + (r & 3)] = a;
          }
        } else {
          const int base = (lyr - 1) * 512;  // input = h_{lyr-1}, recur = h_{lyr}
          float xx[16];
#pragma unroll
          for (int k = 0; k < 8; ++k) xx[k]     = aload(hb + base + k * 64 + lane);
#pragma unroll
          for (int k = 0; k < 8; ++k) xx[8 + k] = aload(hb + base + 512 + k * 64 + lane);
#pragma unroll
          for (int r = 0; r < 8; ++r) {
            float a = 0.f;
#pragma unroll
            for (int k = 0; k < 16; ++k) a += wreg[r][k] * xx[k];
            a = wsum(a) + bsum[r];
            if (lane == 0) gates[lyr * 16 + ((wv & 1) * 2 + (r >> 2)) * 4 + (r & 3)] = a;
          }
        }
      }
    }
    __syncthreads();  // #1: gates, sro, swex visible block-wide

    // ---- pointwise cell update (4 units x 3 layers) ----
    if (tid < 12) {
      const int l = tid >> 2, q = tid & 3;
      const int pl = s - l;
      if (pl >= 0 && pl < NPOS) {
        const float gi = gates[l * 16 + q];
        const float gf = gates[l * 16 + 4 + q];
        const float gg = gates[l * 16 + 8 + q];
        const float go = gates[l * 16 + 12 + q];
        const float cn = sigm(gf) * csto[tid] + sigm(gi) * tanhf(gg);
        const float hn = sigm(go) * tanhf(cn);
        csto[tid] = cn;
        const int u = ub + q;
        astore(h_buf + ((s + 1) & 1) * 1536 + l * 512 + u, hn);
        if (l == 2) astore(rnn_ring + (pl & 7) * 512 + u, hn);
      }
    }

    // ---- attn A: energies, pure compute (ca hoisted; 2 rows per wave) ----
    if (p1 >= 0 && p1 < NPOS) {
      float a0 = 0.f, a1 = 0.f;
#pragma unroll
      for (int k = 0; k < 8; ++k) {
        a0 += ca0[k] * sro[k * 64 + lane];
        a1 += ca1[k] * sro[k * 64 + lane];
      }
      a0 = wsum(a0);
      a1 = wsum(a1);
      if (lane == 0) {
        float* eb = e_ring + (p1 & 1) * 2048 + bid * 16 + wv * 2;
        astore(eb, a0);
        astore(eb + 1, a1);
      }
    }

    // ---- attn C: pure compute (cc hoisted; 1 dim/thread) ----
    if (p3 >= 0 && p3 < NPOS) {
      float a = 0.f;
#pragma unroll
      for (int j = 0; j < 16; ++j) a += swex[j] * cc[j];
      astore(P_ring + (p3 & 1) * (128 * 512) + bid * 512 + tid, a);
    }

    // ---- attn D1: 128 -> 16 partial combine (blocks 0..15) ----
    if (bid < 16 && p4 >= 0 && p4 < NPOS) {
      const float* Pb = P_ring + (p4 & 1) * (128 * 512) + (bid * 8) * 512;
      float q0 = 0.f;
#pragma unroll
      for (int k = 0; k < 8; ++k) q0 += aload(Pb + k * 512 + tid);
      astore(Q_ring + (p4 & 1) * 8192 + bid * 512 + tid, q0);
    }

    // ---- attn D2: 16 -> 1 combine (block 16) ----
    if (bid == 16 && p5 >= 0 && p5 < NPOS) {
      const float* Qb = Q_ring + (p5 & 1) * 8192;
      float c0 = 0.f;
#pragma unroll
      for (int k = 0; k < 16; ++k) c0 += aload(Qb + k * 512 + tid);
      astore(ctx_ring + (p5 & 63) * 512 + tid, c0);
    }

    // ---- attn B: global softmax over 2048 energies (block 17, wave 7) ----
    if (bid == 17 && wv == 7 && p2 >= 0 && p2 < NPOS) {
      const float* eb = e_ring + (p2 & 1) * 2048;
      float e[32];
#pragma unroll
      for (int k = 0; k < 32; ++k) e[k] = aload(eb + k * 64 + lane);
      float m = e[0];
#pragma unroll
      for (int k = 1; k < 32; ++k) m = fmaxf(m, e[k]);
      m = wmax(m);
      float ssum = 0.f;
#pragma unroll
      for (int k = 0; k < 32; ++k) { e[k] = expf(e[k] - m); ssum += e[k]; }
      ssum = wsum(ssum);
      const float inv = 1.f / ssum;
      float* wb = w_ring + (p2 & 1) * 2048;
#pragma unroll
      for (int k = 0; k < 32; ++k) astore(wb + k * 64 + lane, e[k] * inv);
    }

    // ---- proj1: z[v] = w_out[v] . [rnn|ctx] (wave 6 of blocks 0..63) ----
    if (bid < 64 && wv == 6 && p6 >= 0 && p6 < NPOS) {
      const float* rr6 = rnn_ring + (p6 & 7) * 512;
      const float* cr6 = ctx_ring + (p6 & 63) * 512;
      float a = 0.f;
#pragma unroll
      for (int k = 0; k < 8; ++k) a += wp[k] * aload(rr6 + k * 64 + lane);
#pragma unroll
      for (int k = 0; k < 8; ++k) a += wp[8 + k] * aload(cr6 + k * 64 + lane);
      a = wsum(a);
      if (lane == 0) astore(z_ring + (p6 & 1) * 64 + bid, a + bz);
    }

    // ---- proj2: log_softmax + output write (block 18, wave 7) ----
    if (bid == 18 && wv == 7 && p7 >= 0 && p7 < NPOS) {
      const float z = aload(z_ring + (p7 & 1) * 64 + lane);
      const float M = wmax(z);
      const float ls = M + logf(wsum(expf(z - M)));
      out[((size_t)(p7 & 31) * 99 + (p7 >> 5)) * 64 + lane] = z - ls;
    }

    // ---- grid barrier: relaxed flags + per-wave vmem drains (r9-proven) ----
    asm volatile("s_waitcnt vmcnt(0)" ::: "memory");
    __syncthreads();
    if (tid == 0) astore_i(arrive + bid * 16, s + 1);
    if (tid < NBLK)
      while (aload_i(arrive + tid * 16) < s + 1) __builtin_amdgcn_s_sleep(1);
    asm volatile("" ::: "memory");
    __syncthreads();
  }
}

extern "C" void kernel_launch(void* const* d_in, const int* in_sizes, int n_in,
                              void* d_out, int out_size, void* d_ws, size_t ws_size,
                              hipStream_t stream) {
  (void)in_sizes; (void)n_in; (void)out_size; (void)ws_size;
  const float* ctx_t = (const float*)d_in[0];
  const int*   gt    = (const int*)d_in[1];
  const float* emb   = (const float*)d_in[3];
  const float* w_out = (const float*)d_in[4];
  const float* b_out = (const float*)d_in[5];
  const float* wi0 = (const float*)d_in[6];
  const float* wh0 = (const float*)d_in[7];
  const float* bi0 = (const float*)d_in[8];
  const float* bh0 = (const float*)d_in[9];
  const float* wi1 = (const float*)d_in[10];
  const float* wh1 = (const float*)d_in[11];
  const float* bi1 = (const float*)d_in[12];
  const float* bh1 = (const float*)d_in[13];
  const float* wi2 = (const float*)d_in[14];
  const float* wh2 = (const float*)d_in[15];
  const float* bi2 = (const float*)d_in[16];
  const float* bh2 = (const float*)d_in[17];
  float* out = (float*)d_out;
  float* ws  = (float*)d_ws;

  hipLaunchKernelGGL(speller_init, dim3(20), dim3(256), 0, stream, ws);

  hipLaunchKernelGGL(speller_main, dim3(NBLK), dim3(NTHR), 0, stream,
                     ctx_t, gt, emb, w_out, b_out,
                     wi0, wh0, bi0, bh0,
                     wi1, wh1, bi1, bh1,
                     wi2, wh2, bi2, bh2,
                     out, ws);
}

// Round 15
// 24225.064 us; speedup vs baseline: 1.9871x; 1.7909x over previous
//
#include <hip/hip_runtime.h>
#include <math.h>

#define NBLK 128
#define NTHR 512
#define NPOS 3168     // 99 steps * 32 batch
#define NSTAGES 3177  // last proj-phase2 at s = 3167 + 9
#define HIDN 512
#define TT 2048
#define LL 100

__device__ __forceinline__ float aload(const float* p) {
  return __hip_atomic_load((float*)p, __ATOMIC_RELAXED, __HIP_MEMORY_SCOPE_AGENT);
}
__device__ __forceinline__ void astore(float* p, float v) {
  __hip_atomic_store(p, v, __ATOMIC_RELAXED, __HIP_MEMORY_SCOPE_AGENT);
}
__device__ __forceinline__ int aload_i(const int* p) {
  return __hip_atomic_load((int*)p, __ATOMIC_RELAXED, __HIP_MEMORY_SCOPE_AGENT);
}
__device__ __forceinline__ void astore_i(int* p, int v) {
  __hip_atomic_store(p, v, __ATOMIC_RELAXED, __HIP_MEMORY_SCOPE_AGENT);
}
__device__ __forceinline__ float wsum(float v) {
#pragma unroll
  for (int o = 32; o; o >>= 1) v += __shfl_xor(v, o);
  return v;
}
__device__ __forceinline__ float wmax(float v) {
#pragma unroll
  for (int o = 32; o; o >>= 1) v = fmaxf(v, __shfl_xor(v, o));
  return v;
}
__device__ __forceinline__ float sigm(float x) { return 1.f / (1.f + expf(-x)); }

extern "C" __global__ void speller_init(float* ws) {
  const int i = blockIdx.x * blockDim.x + threadIdx.x;
  if (i < 5120) ws[i] = 0.f;  // padded arrive flags (2048 ints) + h double buffers (3072 floats)
}

// Champion structure (r9, 24.7 ms): single end-of-stage relaxed-flag barrier,
// attn loads issued POST-sync (behind the LSTM critical chain). Lessons baked
// in: (r4->r9) acquire-per-poll cache maintenance was 2x; (r12) a second flag
// family adds a serial propagation latency; (r13) loop-carried prefetch regs
// spill to scratch; (r14) bulk loads issued ahead of the critical-path h
// loads delay the gate math via in-order vmcnt. Critical loads first, bulk
// loads behind the chain.
extern "C" __global__ __launch_bounds__(NTHR, 2)
void speller_main(const float* __restrict__ ctx_t, const int* __restrict__ gt,
                  const float* __restrict__ emb, const float* __restrict__ w_out,
                  const float* __restrict__ b_out,
                  const float* __restrict__ wi0, const float* __restrict__ wh0,
                  const float* __restrict__ bi0, const float* __restrict__ bh0,
                  const float* __restrict__ wi1, const float* __restrict__ wh1,
                  const float* __restrict__ bi1, const float* __restrict__ bh1,
                  const float* __restrict__ wi2, const float* __restrict__ wh2,
                  const float* __restrict__ bi2, const float* __restrict__ bh2,
                  float* __restrict__ out, float* __restrict__ ws)
{
  const int bid = blockIdx.x, tid = threadIdx.x;
  const int lane = tid & 63, wv = tid >> 6;
  const int ub = bid * 4;  // this block's 4 hidden units (per layer)

  // ---------------- workspace layout (197,760 floats = 791 KB) ----------------
  int*   arrive   = (int*)ws;               // [128][16] one cacheline per block
  float* h_buf    = ws + 2048;              // [2][3][512]
  float* rnn_ring = ws + 5120;              // [8][512]
  float* ctx_ring = ws + 9216;              // [64][512]
  float* e_ring   = ws + 41984;             // [2][2048]
  float* w_ring   = ws + 46080;             // [2][2048]
  float* P_ring   = ws + 50176;             // [2][128][512]
  float* Q_ring   = ws + 181248;            // [2][16][512]
  float* z_ring   = ws + 197632;            // [2][64]

  __shared__ float sro[HIDN];   // rnn_out for attention energies
  __shared__ float swex[16];    // this block's 16 attention weights (phase C)
  __shared__ float gates[48];   // l*16 + g*4 + q
  __shared__ float csto[12];    // cell state, 4 units x 3 layers

  if (tid < 12) csto[tid] = 0.f;

  // ---------------- weight preload into VGPRs ----------------
  // waves 0,1: layer 0 (gates {0,1}/{2,3} x 4 units, 17 chunks incl. emb)
  // waves 2,3: layer 1 ; waves 4,5: layer 2 (16 chunks)
  const int lyr = wv >> 1;  // 0..2 for wv 0..5
  float wreg[8][17];
  float bsum[8];
  if (wv < 6) {
    if (lyr == 0) {
#pragma unroll
      for (int r = 0; r < 8; ++r) {
        const int R = (wv * 2 + (r >> 2)) * 512 + ub + (r & 3);
#pragma unroll
        for (int k = 0; k < 9; ++k) wreg[r][k] = wi0[(size_t)R * 576 + k * 64 + lane];
#pragma unroll
        for (int k = 0; k < 8; ++k) wreg[r][9 + k] = wh0[(size_t)R * 512 + k * 64 + lane];
        bsum[r] = bi0[R] + bh0[R];
      }
    } else {
      const float* wiL = (lyr == 1) ? wi1 : wi2;
      const float* whL = (lyr == 1) ? wh1 : wh2;
      const float* biL = (lyr == 1) ? bi1 : bi2;
      const float* bhL = (lyr == 1) ? bh1 : bh2;
#pragma unroll
      for (int r = 0; r < 8; ++r) {
        const int R = ((wv & 1) * 2 + (r >> 2)) * 512 + ub + (r & 3);
#pragma unroll
        for (int k = 0; k < 8; ++k) wreg[r][k] = wiL[(size_t)R * 512 + k * 64 + lane];
#pragma unroll
        for (int k = 0; k < 8; ++k) wreg[r][8 + k] = whL[(size_t)R * 512 + k * 64 + lane];
        bsum[r] = biL[R] + bhL[R];
      }
    }
  }
  // projection weights: wave 6 of blocks 0..63 holds w_out row `bid`
  float wp[16];
  float bz = 0.f;
  if (bid < 64 && wv == 6) {
#pragma unroll
    for (int k = 0; k < 16; ++k) wp[k] = w_out[(size_t)bid * 1024 + k * 64 + lane];
    bz = b_out[bid];
  }

  for (int s = 0; s < NSTAGES; ++s) {
    const float* hb = h_buf + (s & 1) * 1536;
    const int p1 = s - 3, p2 = s - 4, p3 = s - 5, p4 = s - 6,
              p5 = s - 7, p6 = s - 8, p7 = s - 9;

    // ---- pre-barrier LDS staging ----
    if (p1 >= 0 && p1 < NPOS) sro[tid] = aload(rnn_ring + (p1 & 7) * 512 + tid);
    if (p3 >= 0 && p3 < NPOS && tid < 16)
      swex[tid] = aload(w_ring + (p3 & 1) * 2048 + bid * 16 + tid);

    // ---- LSTM gather + register dot products (waves 0..5) ----
    if (wv < 6) {
      const int pL = s - lyr;
      if (pL >= 0 && pL < NPOS) {
        float x[17];
        if (lyr == 0) {
          const int b0 = s & 31, t0 = s >> 5;
          const int g0 = gt[b0 * LL + t0];
          if (t0 == 0) {
            x[0] = (lane == g0) ? 1.f : 0.f;
            const float* cb = ctx_t + (size_t)b0 * TT * HIDN;
#pragma unroll
            for (int k = 0; k < 8; ++k) x[1 + k] = cb[k * 64 + lane];
          } else {
            x[0] = emb[g0 * 64 + lane];
            const float* cr = ctx_ring + ((s - 32) & 63) * 512;
#pragma unroll
            for (int k = 0; k < 8; ++k) x[1 + k] = aload(cr + k * 64 + lane);
          }
#pragma unroll
          for (int k = 0; k < 8; ++k) x[9 + k] = aload(hb + k * 64 + lane);
#pragma unroll
          for (int r = 0; r < 8; ++r) {
            float a = 0.f;
#pragma unroll
            for (int k = 0; k < 17; ++k) a += wreg[r][k] * x[k];
            a = wsum(a) + bsum[r];
            if (lane == 0) gates[(wv * 2 + (r >> 2)) * 4 + (r & 3)] = a;
          }
        } else {
          const int base = (lyr - 1) * 512;  // input = h_{lyr-1}, recur = h_{lyr}
          float xx[16];
#pragma unroll
          for (int k = 0; k < 8; ++k) xx[k]     = aload(hb + base + k * 64 + lane);
#pragma unroll
          for (int k = 0; k < 8; ++k) xx[8 + k] = aload(hb + base + 512 + k * 64 + lane);
#pragma unroll
          for (int r = 0; r < 8; ++r) {
            float a = 0.f;
#pragma unroll
            for (int k = 0; k < 16; ++k) a += wreg[r][k] * xx[k];
            a = wsum(a) + bsum[r];
            if (lane == 0) gates[lyr * 16 + ((wv & 1) * 2 + (r >> 2)) * 4 + (r & 3)] = a;
          }
        }
      }
    }
    __syncthreads();  // gates, sro, swex visible block-wide

    // ---- pointwise cell update (4 units x 3 layers) ----
    if (tid < 12) {
      const int l = tid >> 2, q = tid & 3;
      const int pl = s - l;
      if (pl >= 0 && pl < NPOS) {
        const float gi = gates[l * 16 + q];
        const float gf = gates[l * 16 + 4 + q];
        const float gg = gates[l * 16 + 8 + q];
        const float go = gates[l * 16 + 12 + q];
        const float cn = sigm(gf) * csto[tid] + sigm(gi) * tanhf(gg);
        const float hn = sigm(go) * tanhf(cn);
        csto[tid] = cn;
        const int u = ub + q;
        astore(h_buf + ((s + 1) & 1) * 1536 + l * 512 + u, hn);
        if (l == 2) astore(rnn_ring + (pl & 7) * 512 + u, hn);
      }
    }

    // ---- attn A: energies, 16 T-rows per block (2 per wave) ----
    if (p1 >= 0 && p1 < NPOS) {
      const int b1 = p1 & 31;
#pragma unroll
      for (int jj = 0; jj < 2; ++jj) {
        const int j = bid * 16 + wv * 2 + jj;
        const float* crow = ctx_t + ((size_t)b1 * TT + j) * HIDN;
        float a = 0.f;
#pragma unroll
        for (int k = 0; k < 8; ++k) a += crow[k * 64 + lane] * sro[k * 64 + lane];
        a = wsum(a);
        if (lane == 0) astore(e_ring + (p1 & 1) * 2048 + j, a);
      }
    }

    // ---- attn C: weighted partial sum, 16 rows per block (waves spread 512thr) ----
    if (p3 >= 0 && p3 < NPOS) {
      const int b3 = p3 & 31;
      const float* cb3 = ctx_t + ((size_t)b3 * TT + bid * 16) * HIDN;
      float* Pb = P_ring + (p3 & 1) * (128 * 512) + bid * 512;
      for (int c = tid; c < 512; c += NTHR) {
        float a0 = 0.f;
#pragma unroll
        for (int j = 0; j < 16; ++j) a0 += swex[j] * cb3[j * HIDN + c];
        astore(Pb + c, a0);
      }
    }

    // ---- attn D1: 128 -> 16 partial combine (blocks 0..15) ----
    if (bid < 16 && p4 >= 0 && p4 < NPOS) {
      const float* Pb = P_ring + (p4 & 1) * (128 * 512) + (bid * 8) * 512;
      float* Qb = Q_ring + (p4 & 1) * 8192 + bid * 512;
      for (int c = tid; c < 512; c += NTHR) {
        float q0 = 0.f;
#pragma unroll
        for (int k = 0; k < 8; ++k) q0 += aload(Pb + k * 512 + c);
        astore(Qb + c, q0);
      }
    }

    // ---- attn D2: 16 -> 1 combine (block 16) ----
    if (bid == 16 && p5 >= 0 && p5 < NPOS) {
      const float* Qb = Q_ring + (p5 & 1) * 8192;
      float* cr = ctx_ring + (p5 & 63) * 512;
      for (int c = tid; c < 512; c += NTHR) {
        float c0 = 0.f;
#pragma unroll
        for (int k = 0; k < 16; ++k) c0 += aload(Qb + k * 512 + c);
        astore(cr + c, c0);
      }
    }

    // ---- attn B: global softmax over 2048 energies (block 17, wave 7) ----
    if (bid == 17 && wv == 7 && p2 >= 0 && p2 < NPOS) {
      const float* eb = e_ring + (p2 & 1) * 2048;
      float e[32];
#pragma unroll
      for (int k = 0; k < 32; ++k) e[k] = aload(eb + k * 64 + lane);
      float m = e[0];
#pragma unroll
      for (int k = 1; k < 32; ++k) m = fmaxf(m, e[k]);
      m = wmax(m);
      float ssum = 0.f;
#pragma unroll
      for (int k = 0; k < 32; ++k) { e[k] = expf(e[k] - m); ssum += e[k]; }
      ssum = wsum(ssum);
      const float inv = 1.f / ssum;
      float* wb = w_ring + (p2 & 1) * 2048;
#pragma unroll
      for (int k = 0; k < 32; ++k) astore(wb + k * 64 + lane, e[k] * inv);
    }

    // ---- proj1: z[v] = w_out[v] . [rnn|ctx] (wave 6 of blocks 0..63) ----
    if (bid < 64 && wv == 6 && p6 >= 0 && p6 < NPOS) {
      const float* rr6 = rnn_ring + (p6 & 7) * 512;
      const float* cr6 = ctx_ring + (p6 & 63) * 512;
      float a = 0.f;
#pragma unroll
      for (int k = 0; k < 8; ++k) a += wp[k] * aload(rr6 + k * 64 + lane);
#pragma unroll
      for (int k = 0; k < 8; ++k) a += wp[8 + k] * aload(cr6 + k * 64 + lane);
      a = wsum(a);
      if (lane == 0) astore(z_ring + (p6 & 1) * 64 + bid, a + bz);
    }

    // ---- proj2: log_softmax + output write (block 18, wave 7) ----
    if (bid == 18 && wv == 7 && p7 >= 0 && p7 < NPOS) {
      const float z = aload(z_ring + (p7 & 1) * 64 + lane);
      const float M = wmax(z);
      const float ls = M + logf(wsum(expf(z - M)));
      out[((size_t)(p7 & 31) * 99 + (p7 >> 5)) * 64 + lane] = z - ls;
    }

    // ---- grid barrier: RELAXED flags, no per-poll cache maintenance ----
    // Each wave drains its own stores (vmcnt per-wave) BEFORE syncthreads, so
    // all block data is at the coherence point before tid 0's flag store.
    // Polls are relaxed loads (no buffer_inv per iteration); all shared data
    // moves via coherence-point atomics anyway.
    asm volatile("s_waitcnt vmcnt(0)" ::: "memory");
    __syncthreads();
    if (tid == 0) astore_i(arrive + bid * 16, s + 1);
    if (tid < NBLK)
      while (aload_i(arrive + tid * 16) < s + 1) __builtin_amdgcn_s_sleep(1);
    asm volatile("" ::: "memory");
    __syncthreads();
  }
}

extern "C" void kernel_launch(void* const* d_in, const int* in_sizes, int n_in,
                              void* d_out, int out_size, void* d_ws, size_t ws_size,
                              hipStream_t stream) {
  (void)in_sizes; (void)n_in; (void)out_size; (void)ws_size;
  const float* ctx_t = (const float*)d_in[0];
  const int*   gt    = (const int*)d_in[1];
  const float* emb   = (const float*)d_in[3];
  const float* w_out = (const float*)d_in[4];
  const float* b_out = (const float*)d_in[5];
  const float* wi0 = (const float*)d_in[6];
  const float* wh0 = (const float*)d_in[7];
  const float* bi0 = (const float*)d_in[8];
  const float* bh0 = (const float*)d_in[9];
  const float* wi1 = (const float*)d_in[10];
  const float* wh1 = (const float*)d_in[11];
  const float* bi1 = (const float*)d_in[12];
  const float* bh1 = (const float*)d_in[13];
  const float* wi2 = (const float*)d_in[14];
  const float* wh2 = (const float*)d_in[15];
  const float* bi2 = (const float*)d_in[16];
  const float* bh2 = (const float*)d_in[17];
  float* out = (float*)d_out;
  float* ws  = (float*)d_ws;

  hipLaunchKernelGGL(speller_init, dim3(20), dim3(256), 0, stream, ws);

  // Plain (non-cooperative) launch: 128 blocks on 256 CUs are always
  // co-resident; the barrier is hand-rolled flags (r8 validated).
  hipLaunchKernelGGL(speller_main, dim3(NBLK), dim3(NTHR), 0, stream,
                     ctx_t, gt, emb, w_out, b_out,
                     wi0, wh0, bi0, bh0,
                     wi1, wh1, bi1, bh1,
                     wi2, wh2, bi2, bh2,
                     out, ws);
}